// Round 15
// baseline (256.934 us; speedup 1.0000x reference)
//
#include <hip/hip_runtime.h>
#include <hip/hip_bf16.h>
#include <math.h>

#define N_NODES 50000
#define N_EDGES 640000
#define HEADS 4
#define CDIM 32
#define HC 128          // HEADS*CDIM
#define DIN 128
#define DOUT 32
#define NEG_SLOPE 0.2f
#define TPAD 136        // 128 + 8 bf16 pad -> 2-way bank aliasing (free)
#define BCAP 64         // bucket capacity; P(deg>64)~1e-17 for Binom(640K,1/50K)
#define ZERO_NB ((N_NODES + 255) / 256)             // 196
#define WT_NB (2 * DIN * HC / 256)                  // 128
#define FILL_NB (N_EDGES / 256)                     // 2500
#define TF_NB ((N_NODES + 63) / 64)                 // 782

typedef __hip_bfloat16 bf16;
typedef __attribute__((ext_vector_type(8))) short short8;
typedef __attribute__((ext_vector_type(4))) float floatx4;

static __device__ __forceinline__ float bflo(unsigned w) { return __uint_as_float(w << 16); }
static __device__ __forceinline__ float bfhi(unsigned w) { return __uint_as_float(w & 0xFFFF0000u); }
static __device__ __forceinline__ unsigned short f2bf(float f) {
    union { bf16 h; unsigned short u; } cv; cv.h = __float2bfloat16(f); return cv.u;
}

// Prep: zero cnt | W^T -> bf16 (for coalesced MFMA B-fragment reads) | cvec.
__global__ __launch_bounds__(256) void k_prep(
    unsigned* __restrict__ cnt,
    const float* __restrict__ Wl, const float* __restrict__ Wr,
    const float* __restrict__ bias, const float* __restrict__ Wp,
    const float* __restrict__ bp,
    bf16* __restrict__ WlT, bf16* __restrict__ WrT, float* __restrict__ cvec)
{
    const int t = threadIdx.x, b = blockIdx.x;
    if (b < ZERO_NB) {
        const int i = b * 256 + t;
        if (i < N_NODES) cnt[i] = 0u;
    } else if (b < ZERO_NB + WT_NB) {
        const int i = (b - ZERO_NB) * 256 + t;      // [0, 32768)
        if (i < DIN * HC) {
            const int c = i >> 7, j = i & 127;      // W[c][j]
            WlT[j * DIN + c] = __float2bfloat16(Wl[i]);
        } else {
            const int i2 = i - DIN * HC;
            const int c = i2 >> 7, j = i2 & 127;
            WrT[j * DIN + c] = __float2bfloat16(Wr[i2]);
        }
    } else if (t < DOUT) {
        float v = bp[t];
        for (int c = 0; c < HC; c++) v += bias[c] * Wp[c * DOUT + t];
        cvec[t] = v;
    }
}

// Fused bucket-fill + MFMA transform, INTERLEAVED 3:1 so every CU hosts both
// latency-bound scatter waves and compute-bound MFMA waves concurrently
// (round-14 ordered the phases back-to-back -> they serialized; m114-style
// pipe overlap needs true co-residency).
__global__ __launch_bounds__(256) void k_fill_tf(
    const int* __restrict__ ei, unsigned* __restrict__ cnt,
    int* __restrict__ srcs,             // [N_NODES][BCAP]
    const float* __restrict__ x,
    const bf16* __restrict__ WlT, const bf16* __restrict__ WrT,
    bf16* __restrict__ xl, bf16* __restrict__ xr)
{
    __shared__ __align__(16) unsigned short xs[64][TPAD];   // 17.4 KB
    const int t = threadIdx.x, b = blockIdx.x;

    // interleave: b%4==1 && b/4<TF_NB -> transform tile b/4 (782 blocks);
    // all other blocks -> fill chunk (2500 blocks).
    const bool is_tf = ((b & 3) == 1) && ((b >> 2) < TF_NB);

    if (!is_tf) {                       // ---- bucket fill
        const int ntf_le = (b < 4 * TF_NB) ? ((b + 2) >> 2) : TF_NB;
        const int fi = b - ntf_le;      // 0..FILL_NB-1, bijective
        const int e = fi * 256 + t;
        const int dst = ei[N_EDGES + e];
        const unsigned pos = atomicAdd(&cnt[dst], 1u);
        if (pos < BCAP) srcs[((size_t)dst << 6) + pos] = ei[e];
        return;
    }

    // ---- transform: xl = x@Wl, xr = x@Wr (shared A-fragments, dual MFMA)
    const int n0 = (b >> 2) * 64;
    for (int i = t; i < 64 * DIN / 4; i += 256) {
        const int n = i >> 5, c4 = (i & 31) * 4;
        float4 v = make_float4(0.f, 0.f, 0.f, 0.f);
        if (n0 + n < N_NODES)
            v = *(const float4*)(x + (size_t)(n0 + n) * DIN + c4);
        xs[n][c4]     = f2bf(v.x);
        xs[n][c4 + 1] = f2bf(v.y);
        xs[n][c4 + 2] = f2bf(v.z);
        xs[n][c4 + 3] = f2bf(v.w);
    }
    __syncthreads();

    const int w = t >> 6, lane = t & 63;
    const int m = lane & 15, quad = lane >> 4;

    short8 af[4];
    #pragma unroll
    for (int kk = 0; kk < 4; kk++)
        af[kk] = *(const short8*)&xs[w * 16 + m][kk * 32 + quad * 8];

    #pragma unroll
    for (int jt = 0; jt < 8; jt++) {
        floatx4 aL = {0.f, 0.f, 0.f, 0.f};
        floatx4 aR = {0.f, 0.f, 0.f, 0.f};
        const int row = (jt * 16 + m) * DIN + quad * 8;
        #pragma unroll
        for (int kk = 0; kk < 4; kk++) {
            const short8 bl = *(const short8*)(WlT + row + kk * 32);
            const short8 br = *(const short8*)(WrT + row + kk * 32);
            aL = __builtin_amdgcn_mfma_f32_16x16x32_bf16(af[kk], bl, aL, 0, 0, 0);
            aR = __builtin_amdgcn_mfma_f32_16x16x32_bf16(af[kk], br, aR, 0, 0, 0);
        }
        #pragma unroll
        for (int r = 0; r < 4; r++) {               // C/D: col=m, row=quad*4+r
            const int n = n0 + w * 16 + quad * 4 + r;
            if (n < N_NODES) {
                xl[(size_t)n * HC + jt * 16 + m] = __float2bfloat16(aL[r]);
                xr[(size_t)n * HC + jt * 16 + m] = __float2bfloat16(aR[r]);
            }
        }
    }
}

// Fused logit + exp + aggregate + projection (r11 structure, bucket CSR).
// Lane = (es = lane>>4, hq = lane&15): 4 edge slots x 16 lanes; lane owns
// cols 8hq..8hq+7; head-dot reduce = 2 shuffles; 8 rows in flight per wave.
__global__ __launch_bounds__(256) void k_agg(
    const int* __restrict__ srcs, const unsigned* __restrict__ cnt,
    const unsigned* __restrict__ xl2,   // bf16 xl as uint pairs [N][64]
    const unsigned* __restrict__ xr2,   // bf16 xr as uint pairs [N][64]
    const float* __restrict__ att,
    const float* __restrict__ Wp, const float* __restrict__ cvec,
    float* __restrict__ out)
{
    __shared__ float sWp[HC][DOUT];     // 16 KB
    __shared__ float srow[4][HC];
    const int t = threadIdx.x;
    for (int i = t; i < HC * DOUT; i += 256)
        ((float*)sWp)[i] = Wp[i];
    __syncthreads();

    const int w = t >> 6, lane = t & 63;
    const int node = blockIdx.x * 4 + w;
    const int es = lane >> 4, hq = lane & 15;
    const int c0 = hq * 8;

    const uint4 xru = ((const uint4*)(xr2 + (size_t)node * 64))[hq];
    float xr_[8];
    xr_[0] = bflo(xru.x); xr_[1] = bfhi(xru.x);
    xr_[2] = bflo(xru.y); xr_[3] = bfhi(xru.y);
    xr_[4] = bflo(xru.z); xr_[5] = bfhi(xru.z);
    xr_[6] = bflo(xru.w); xr_[7] = bfhi(xru.w);
    const float4 av0 = ((const float4*)att)[hq * 2];
    const float4 av1 = ((const float4*)att)[hq * 2 + 1];
    const float a_[8] = {av0.x, av0.y, av0.z, av0.w, av1.x, av1.y, av1.z, av1.w};

    unsigned cn = cnt[node]; if (cn > BCAP) cn = BCAP;
    const unsigned lo = (unsigned)node << 6, hi = lo + cn;
    float s_run = 0.f;
    float acc[8] = {0.f, 0.f, 0.f, 0.f, 0.f, 0.f, 0.f, 0.f};

    for (unsigned base = lo; base < hi; base += 64) {
        const unsigned j = base + lane;
        const int srcj = (j < hi) ? srcs[j] : 0;
        const int cnt2 = (int)((hi - base < 64u) ? (hi - base) : 64u);
        // slot es handles edges es, es+4, es+8, ... double-buffered (xa, xb)
        int sj = __shfl(srcj, es, 64);
        uint4 xa = ((const uint4*)(xl2 + ((size_t)((es < cnt2) ? sj : 0) << 6)))[hq];
        sj = __shfl(srcj, (es + 4) & 63, 64);
        uint4 xb = ((const uint4*)(xl2 + ((size_t)((es + 4 < cnt2) ? sj : 0) << 6)))[hq];
        for (int i = 0; i < cnt2; i += 8) {
            #pragma unroll
            for (int u = 0; u < 2; u++) {           // u=0 -> xa, u=1 -> xb
                const int eidx = i + es + 4 * u;
                const uint4 cur = u ? xb : xa;
                const int ii = eidx + 8;
                sj = __shfl(srcj, ii & 63, 64);
                const uint4 nxt = ((const uint4*)(xl2 + ((size_t)((ii < cnt2) ? sj : 0) << 6)))[hq];
                if (u) xb = nxt; else xa = nxt;

                float x_[8];
                x_[0] = bflo(cur.x); x_[1] = bfhi(cur.x);
                x_[2] = bflo(cur.y); x_[3] = bfhi(cur.y);
                x_[4] = bflo(cur.z); x_[5] = bfhi(cur.z);
                x_[6] = bflo(cur.w); x_[7] = bfhi(cur.w);
                float p = 0.f;
                #pragma unroll
                for (int k = 0; k < 8; k++) {
                    float v = x_[k] + xr_[k];
                    v = fmaxf(v, NEG_SLOPE * v);
                    p = fmaf(a_[k], v, p);
                }
                p += __shfl_xor(p, 1, 64);
                p += __shfl_xor(p, 2, 64);          // logit(edge eidx, head)
                const float e_ = (eidx < cnt2) ? __expf(p) : 0.f;
                s_run += e_;
                #pragma unroll
                for (int k = 0; k < 8; k++) acc[k] = fmaf(x_[k], e_, acc[k]);
            }
        }
    }
    // combine the 4 edge slots (lanes differing in bits 4,5; same cols)
    s_run += __shfl_xor(s_run, 16, 64);
    s_run += __shfl_xor(s_run, 32, 64);
    #pragma unroll
    for (int k = 0; k < 8; k++) {
        acc[k] += __shfl_xor(acc[k], 16, 64);
        acc[k] += __shfl_xor(acc[k], 32, 64);
    }
    const float rden = 1.f / (s_run + 1e-16f);

    if (es == 0) {
        float4 r0 = {acc[0] * rden, acc[1] * rden, acc[2] * rden, acc[3] * rden};
        float4 r1 = {acc[4] * rden, acc[5] * rden, acc[6] * rden, acc[7] * rden};
        *(float4*)&srow[w][c0]     = r0;
        *(float4*)&srow[w][c0 + 4] = r1;
    }
    // same-wave LDS RAW: in-order DS pipe, no barrier needed
    const int jj = lane & 31, half = lane >> 5;
    float pacc = 0.f;
    const int cb = half * 64;
    #pragma unroll 8
    for (int c = 0; c < 64; c++)
        pacc += srow[w][cb + c] * sWp[cb + c][jj];
    pacc += __shfl_down(pacc, 32, 64);
    if (lane < 32)
        out[(size_t)node * DOUT + jj] = pacc + cvec[jj];
}

extern "C" void kernel_launch(void* const* d_in, const int* in_sizes, int n_in,
                              void* d_out, int out_size, void* d_ws, size_t ws_size,
                              hipStream_t stream)
{
    const float* x    = (const float*)d_in[0];
    const int*   ei   = (const int*)d_in[1];
    const float* Wl   = (const float*)d_in[2];
    const float* Wr   = (const float*)d_in[3];
    const float* att  = (const float*)d_in[4];
    const float* bias = (const float*)d_in[5];
    const float* Wp   = (const float*)d_in[6];
    const float* bp   = (const float*)d_in[7];
    float* out = (float*)d_out;

    // workspace (~38.7 MB):
    // xl bf16[N*HC] | xr bf16[N*HC] | WlT bf16[HC*DIN] | WrT bf16[HC*DIN]
    // | cvec f32[32] | cnt u32[N] | srcs i32[N*BCAP]
    bf16* xl       = (bf16*)d_ws;
    bf16* xr       = xl + (size_t)N_NODES * HC;
    bf16* WlT      = xr + (size_t)N_NODES * HC;
    bf16* WrT      = WlT + DIN * HC;
    float* cvec    = (float*)(WrT + DIN * HC);
    unsigned* cnt  = (unsigned*)(cvec + DOUT);
    int* srcs      = (int*)(cnt + N_NODES);

    k_prep<<<ZERO_NB + WT_NB + 1, 256, 0, stream>>>(cnt, Wl, Wr, bias, Wp, bp,
                                                    WlT, WrT, cvec);
    k_fill_tf<<<FILL_NB + TF_NB, 256, 0, stream>>>(ei, cnt, srcs, x,
                                                   WlT, WrT, xl, xr);
    k_agg<<<N_NODES / 4, 256, 0, stream>>>(srcs, cnt,
        (const unsigned*)xl, (const unsigned*)xr, att, Wp, cvec, out);
}

// Round 16
// 193.271 us; speedup vs baseline: 1.3294x; 1.3294x over previous
//
#include <hip/hip_runtime.h>
#include <hip/hip_bf16.h>
#include <math.h>

#define N_NODES 50000
#define N_EDGES 640000
#define HEADS 4
#define CDIM 32
#define HC 128          // HEADS*CDIM
#define DIN 128
#define DOUT 32
#define NEG_SLOPE 0.2f
#define TPAD 136        // 128 + 8 bf16 pad -> 2-way bank aliasing (free)
#define BCAP 64         // bucket capacity; P(deg>64)~1e-17 for Binom(640K,1/50K)
#define NPB 16          // nodes per k_agg block (4 waves x 4 sequential)
#define ZERO_NB ((N_NODES + 255) / 256)             // 196
#define WT_NB (2 * DIN * HC / 256)                  // 128
#define WPT_NB (DOUT * HC / 256)                    // 16
#define FILL_NB (N_EDGES / 256)                     // 2500
#define TF_NB ((N_NODES + 63) / 64)                 // 782

typedef __hip_bfloat16 bf16;
typedef __attribute__((ext_vector_type(8))) short short8;
typedef __attribute__((ext_vector_type(4))) float floatx4;

static __device__ __forceinline__ float bflo(unsigned w) { return __uint_as_float(w << 16); }
static __device__ __forceinline__ float bfhi(unsigned w) { return __uint_as_float(w & 0xFFFF0000u); }
static __device__ __forceinline__ unsigned short f2bf(float f) {
    union { bf16 h; unsigned short u; } cv; cv.h = __float2bfloat16(f); return cv.u;
}

// Prep: zero cnt | Wl/Wr^T -> bf16 | Wp^T -> bf16 | cvec = bias@Wp + bp.
__global__ __launch_bounds__(256) void k_prep(
    unsigned* __restrict__ cnt,
    const float* __restrict__ Wl, const float* __restrict__ Wr,
    const float* __restrict__ bias, const float* __restrict__ Wp,
    const float* __restrict__ bp,
    bf16* __restrict__ WlT, bf16* __restrict__ WrT, bf16* __restrict__ WpT,
    float* __restrict__ cvec)
{
    const int t = threadIdx.x, b = blockIdx.x;
    if (b < ZERO_NB) {
        const int i = b * 256 + t;
        if (i < N_NODES) cnt[i] = 0u;
    } else if (b < ZERO_NB + WT_NB) {
        const int i = (b - ZERO_NB) * 256 + t;      // [0, 32768)
        if (i < DIN * HC) {
            const int c = i >> 7, j = i & 127;      // W[c][j]
            WlT[j * DIN + c] = __float2bfloat16(Wl[i]);
        } else {
            const int i2 = i - DIN * HC;
            const int c = i2 >> 7, j = i2 & 127;
            WrT[j * DIN + c] = __float2bfloat16(Wr[i2]);
        }
    } else if (b < ZERO_NB + WT_NB + WPT_NB) {
        const int i = (b - ZERO_NB - WT_NB) * 256 + t;  // [0, 4096)
        const int c = i >> 5, j = i & 31;           // Wp[c][j]
        WpT[j * HC + c] = __float2bfloat16(Wp[i]);
    } else if (t < DOUT) {
        float v = bp[t];
        for (int c = 0; c < HC; c++) v += bias[c] * Wp[c * DOUT + t];
        cvec[t] = v;
    }
}

// Fused bucket-fill (blocks 0..FILL_NB-1 first: latency-bound scatter) +
// MFMA transform (blocks FILL_NB..). r14 ordering — r15's interleave
// regressed (L2 write contention between scatter and streaming stores).
__global__ __launch_bounds__(256) void k_fill_tf(
    const int* __restrict__ ei, unsigned* __restrict__ cnt,
    int* __restrict__ srcs,             // [N_NODES][BCAP]
    const float* __restrict__ x,
    const bf16* __restrict__ WlT, const bf16* __restrict__ WrT,
    bf16* __restrict__ xl, bf16* __restrict__ xr)
{
    __shared__ __align__(16) unsigned short xs[64][TPAD];   // 17.4 KB
    const int t = threadIdx.x, b = blockIdx.x;

    if (b < FILL_NB) {                  // ---- bucket fill
        const int e = b * 256 + t;
        const int dst = ei[N_EDGES + e];
        const unsigned pos = atomicAdd(&cnt[dst], 1u);
        if (pos < BCAP) srcs[((size_t)dst << 6) + pos] = ei[e];
        return;
    }

    // ---- transform: xl = x@Wl, xr = x@Wr (shared A-fragments, dual MFMA)
    const int n0 = (b - FILL_NB) * 64;
    for (int i = t; i < 64 * DIN / 4; i += 256) {
        const int n = i >> 5, c4 = (i & 31) * 4;
        float4 v = make_float4(0.f, 0.f, 0.f, 0.f);
        if (n0 + n < N_NODES)
            v = *(const float4*)(x + (size_t)(n0 + n) * DIN + c4);
        xs[n][c4]     = f2bf(v.x);
        xs[n][c4 + 1] = f2bf(v.y);
        xs[n][c4 + 2] = f2bf(v.z);
        xs[n][c4 + 3] = f2bf(v.w);
    }
    __syncthreads();

    const int w = t >> 6, lane = t & 63;
    const int m = lane & 15, quad = lane >> 4;

    short8 af[4];
    #pragma unroll
    for (int kk = 0; kk < 4; kk++)
        af[kk] = *(const short8*)&xs[w * 16 + m][kk * 32 + quad * 8];

    #pragma unroll
    for (int jt = 0; jt < 8; jt++) {
        floatx4 aL = {0.f, 0.f, 0.f, 0.f};
        floatx4 aR = {0.f, 0.f, 0.f, 0.f};
        const int row = (jt * 16 + m) * DIN + quad * 8;
        #pragma unroll
        for (int kk = 0; kk < 4; kk++) {
            const short8 bl = *(const short8*)(WlT + row + kk * 32);
            const short8 br = *(const short8*)(WrT + row + kk * 32);
            aL = __builtin_amdgcn_mfma_f32_16x16x32_bf16(af[kk], bl, aL, 0, 0, 0);
            aR = __builtin_amdgcn_mfma_f32_16x16x32_bf16(af[kk], br, aR, 0, 0, 0);
        }
        #pragma unroll
        for (int r = 0; r < 4; r++) {               // C/D: col=m, row=quad*4+r
            const int n = n0 + w * 16 + quad * 4 + r;
            if (n < N_NODES) {
                xl[(size_t)n * HC + jt * 16 + m] = __float2bfloat16(aL[r]);
                xr[(size_t)n * HC + jt * 16 + m] = __float2bfloat16(aR[r]);
            }
        }
    }
}

// Fused logit + exp + aggregate + MFMA projection. 16 nodes/block; wave w
// runs 4 sequential edge loops (nodes w*4..w*4+3), writes bf16 rows to LDS;
// waves 0,1 then project [16x128]@[128x32] with 8 MFMAs (j-tile = w).
// Replaces the 64-iter ds_read_b32 dot-product epilogue (~30 us of LDS issue).
__global__ __launch_bounds__(256) void k_agg(
    const int* __restrict__ srcs, const unsigned* __restrict__ cnt,
    const unsigned* __restrict__ xl2,   // bf16 xl as uint pairs [N][64]
    const unsigned* __restrict__ xr2,   // bf16 xr as uint pairs [N][64]
    const float* __restrict__ att,
    const bf16* __restrict__ WpT,       // [DOUT][HC] bf16
    const float* __restrict__ cvec,
    float* __restrict__ out)
{
    __shared__ __align__(16) unsigned short srow[NPB][TPAD];    // 4.35 KB
    const int t = threadIdx.x;
    const int w = t >> 6, lane = t & 63;
    const int es = lane >> 4, hq = lane & 15;

    const float4 av0 = ((const float4*)att)[hq * 2];
    const float4 av1 = ((const float4*)att)[hq * 2 + 1];
    const float a_[8] = {av0.x, av0.y, av0.z, av0.w, av1.x, av1.y, av1.z, av1.w};

    for (int ni = 0; ni < 4; ni++) {
        const int node = blockIdx.x * NPB + w * 4 + ni;

        const uint4 xru = ((const uint4*)(xr2 + (size_t)node * 64))[hq];
        float xr_[8];
        xr_[0] = bflo(xru.x); xr_[1] = bfhi(xru.x);
        xr_[2] = bflo(xru.y); xr_[3] = bfhi(xru.y);
        xr_[4] = bflo(xru.z); xr_[5] = bfhi(xru.z);
        xr_[6] = bflo(xru.w); xr_[7] = bfhi(xru.w);

        unsigned cn = cnt[node]; if (cn > BCAP) cn = BCAP;
        const unsigned lo = (unsigned)node << 6, hi = lo + cn;
        float s_run = 0.f;
        float acc[8] = {0.f, 0.f, 0.f, 0.f, 0.f, 0.f, 0.f, 0.f};

        for (unsigned base = lo; base < hi; base += 64) {
            const unsigned j = base + lane;
            const int srcj = (j < hi) ? srcs[j] : 0;
            const int cnt2 = (int)((hi - base < 64u) ? (hi - base) : 64u);
            // slot es: edges es, es+4, ... double-buffered (xa, xb)
            int sj = __shfl(srcj, es, 64);
            uint4 xa = ((const uint4*)(xl2 + ((size_t)((es < cnt2) ? sj : 0) << 6)))[hq];
            sj = __shfl(srcj, (es + 4) & 63, 64);
            uint4 xb = ((const uint4*)(xl2 + ((size_t)((es + 4 < cnt2) ? sj : 0) << 6)))[hq];
            for (int i = 0; i < cnt2; i += 8) {
                #pragma unroll
                for (int u = 0; u < 2; u++) {       // u=0 -> xa, u=1 -> xb
                    const int eidx = i + es + 4 * u;
                    const uint4 cur = u ? xb : xa;
                    const int ii = eidx + 8;
                    sj = __shfl(srcj, ii & 63, 64);
                    const uint4 nxt = ((const uint4*)(xl2 + ((size_t)((ii < cnt2) ? sj : 0) << 6)))[hq];
                    if (u) xb = nxt; else xa = nxt;

                    float x_[8];
                    x_[0] = bflo(cur.x); x_[1] = bfhi(cur.x);
                    x_[2] = bflo(cur.y); x_[3] = bfhi(cur.y);
                    x_[4] = bflo(cur.z); x_[5] = bfhi(cur.z);
                    x_[6] = bflo(cur.w); x_[7] = bfhi(cur.w);
                    float p = 0.f;
                    #pragma unroll
                    for (int k = 0; k < 8; k++) {
                        float v = x_[k] + xr_[k];
                        v = fmaxf(v, NEG_SLOPE * v);
                        p = fmaf(a_[k], v, p);
                    }
                    p += __shfl_xor(p, 1, 64);
                    p += __shfl_xor(p, 2, 64);      // logit(edge eidx, head)
                    const float e_ = (eidx < cnt2) ? __expf(p) : 0.f;
                    s_run += e_;
                    #pragma unroll
                    for (int k = 0; k < 8; k++) acc[k] = fmaf(x_[k], e_, acc[k]);
                }
            }
        }
        // combine the 4 edge slots
        s_run += __shfl_xor(s_run, 16, 64);
        s_run += __shfl_xor(s_run, 32, 64);
        #pragma unroll
        for (int k = 0; k < 8; k++) {
            acc[k] += __shfl_xor(acc[k], 16, 64);
            acc[k] += __shfl_xor(acc[k], 32, 64);
        }
        const float rden = 1.f / (s_run + 1e-16f);

        if (es == 0) {                  // lane hq stores cols 8hq..8hq+7 (16B)
            union { unsigned short s[8]; uint4 v; } pk;
            #pragma unroll
            for (int k = 0; k < 8; k++) pk.s[k] = f2bf(acc[k] * rden);
            *(uint4*)&srow[w * 4 + ni][hq * 8] = pk.v;
        }
    }
    __syncthreads();

    // ---- MFMA projection: D[16 nodes][32 cols] = srow @ Wp, j-tile = w
    if (w < 2) {
        const int m = lane & 15, quad = lane >> 4;
        short8 af[4];
        #pragma unroll
        for (int kk = 0; kk < 4; kk++)      // A row = node m, k = kk*32+quad*8
            af[kk] = *(const short8*)&srow[m][kk * 32 + quad * 8];
        floatx4 d = {0.f, 0.f, 0.f, 0.f};
        #pragma unroll
        for (int kk = 0; kk < 4; kk++) {
            const short8 bfr = *(const short8*)(WpT + (w * 16 + m) * HC + kk * 32 + quad * 8);
            d = __builtin_amdgcn_mfma_f32_16x16x32_bf16(af[kk], bfr, d, 0, 0, 0);
        }
        const int jj = w * 16 + m;
        const float cv = cvec[jj];
        #pragma unroll
        for (int r = 0; r < 4; r++) {       // D: col=m (j), row=quad*4+r (node)
            const int node = blockIdx.x * NPB + quad * 4 + r;
            out[(size_t)node * DOUT + jj] = d[r] + cv;
        }
    }
}

extern "C" void kernel_launch(void* const* d_in, const int* in_sizes, int n_in,
                              void* d_out, int out_size, void* d_ws, size_t ws_size,
                              hipStream_t stream)
{
    const float* x    = (const float*)d_in[0];
    const int*   ei   = (const int*)d_in[1];
    const float* Wl   = (const float*)d_in[2];
    const float* Wr   = (const float*)d_in[3];
    const float* att  = (const float*)d_in[4];
    const float* bias = (const float*)d_in[5];
    const float* Wp   = (const float*)d_in[6];
    const float* bp   = (const float*)d_in[7];
    float* out = (float*)d_out;

    // workspace (~38.7 MB):
    // xl bf16[N*HC] | xr bf16[N*HC] | WlT bf16[HC*DIN] | WrT bf16[HC*DIN]
    // | WpT bf16[DOUT*HC] | cvec f32[32] | cnt u32[N] | srcs i32[N*BCAP]
    bf16* xl       = (bf16*)d_ws;
    bf16* xr       = xl + (size_t)N_NODES * HC;
    bf16* WlT      = xr + (size_t)N_NODES * HC;
    bf16* WrT      = WlT + DIN * HC;
    bf16* WpT      = WrT + DIN * HC;
    float* cvec    = (float*)(WpT + DOUT * HC);
    unsigned* cnt  = (unsigned*)(cvec + DOUT);
    int* srcs      = (int*)(cnt + N_NODES);

    k_prep<<<ZERO_NB + WT_NB + WPT_NB + 1, 256, 0, stream>>>(
        cnt, Wl, Wr, bias, Wp, bp, WlT, WrT, WpT, cvec);
    k_fill_tf<<<FILL_NB + TF_NB, 256, 0, stream>>>(ei, cnt, srcs, x,
                                                   WlT, WrT, xl, xr);
    k_agg<<<N_NODES / NPB, 256, 0, stream>>>(srcs, cnt,
        (const unsigned*)xl, (const unsigned*)xr, att, WpT, cvec, out);
}